// Round 2
// baseline (174.392 us; speedup 1.0000x reference)
//
#include <hip/hip_runtime.h>
#include <hip/hip_bf16.h>
#include <stdint.h>

typedef __attribute__((ext_vector_type(8))) short short8;
typedef __attribute__((ext_vector_type(8))) _Float16 half8;
typedef __attribute__((ext_vector_type(4))) float f32x4;

__device__ __forceinline__ unsigned short f32_to_bf16_rn(float f) {
    unsigned int u = __float_as_uint(f);
    u += 0x7fffu + ((u >> 16) & 1u);
    return (unsigned short)(u >> 16);
}
__device__ __forceinline__ float bf16_to_f32(unsigned short h) {
    return __uint_as_float(((unsigned int)h) << 16);
}
__device__ __forceinline__ float sigmoidf_(float x) {
    return 1.0f / (1.0f + expf(-x));
}
__device__ __forceinline__ void gload_lds16(const short* g, short* l) {
    __builtin_amdgcn_global_load_lds(
        (const __attribute__((address_space(1))) void*)g,
        (__attribute__((address_space(3))) void*)l, 16, 0, 0);
}

// ---------------- prep: batch [2048][784] f32 -> hi/lo bf16 [2048][800] (k-pad) ----
__global__ void prep_batch(const float* __restrict__ batch,
                           short* __restrict__ Ahi, short* __restrict__ Alo) {
    long idx = (long)blockIdx.x * 256 + threadIdx.x;      // over 2048*800
    if (idx >= 2048L * 800) return;
    long m = idx / 800;
    int  k = (int)(idx - m * 800);
    float v = (k < 784) ? batch[m * 784 + k] : 0.0f;
    unsigned short h = f32_to_bf16_rn(v);
    Ahi[idx] = (short)h;
    Alo[idx] = (short)f32_to_bf16_rn(v - bf16_to_f32(h));
}

// ---------------- prep: W0 [784][512] -> transposed hi/lo [512][800] (k-pad) -------
__global__ void prep_w0t(const float* __restrict__ W0,
                         short* __restrict__ Bhi, short* __restrict__ Blo) {
    __shared__ float tile[32][33];
    int n0 = blockIdx.x * 32, k0 = blockIdx.y * 32;
    int tx = threadIdx.x, ty = threadIdx.y;               // (32,8)
#pragma unroll
    for (int r = 0; r < 4; ++r) {
        int k = k0 + ty + r * 8;
        float v = (k < 784) ? W0[(long)k * 512 + n0 + tx] : 0.0f;
        tile[ty + r * 8][tx] = v;
    }
    __syncthreads();
#pragma unroll
    for (int r = 0; r < 4; ++r) {
        int n = n0 + ty + r * 8;
        float v = tile[tx][ty + r * 8];
        unsigned short h = f32_to_bf16_rn(v);
        Bhi[(long)n * 800 + k0 + tx] = (short)h;
        Blo[(long)n * 800 + k0 + tx] = (short)f32_to_bf16_rn(v - bf16_to_f32(h));
    }
}

// ------- prep: W1n[s] = W1 + noise[s] (s=0 clean) -> transposed hi/lo [s][512][512] -
__global__ void prep_w1t(const float* __restrict__ W1, const float* __restrict__ noise,
                         short* __restrict__ Bhi, short* __restrict__ Blo) {
    __shared__ float tile[32][33];
    int n0 = blockIdx.x * 32, k0 = blockIdx.y * 32, s = blockIdx.z;
    int tx = threadIdx.x, ty = threadIdx.y;               // (32,8)
#pragma unroll
    for (int r = 0; r < 4; ++r) {
        int k = k0 + ty + r * 8;
        float v = W1[(long)k * 512 + n0 + tx];
        if (s > 0) v += noise[((long)s * 512 + k) * 512 + n0 + tx];
        tile[ty + r * 8][tx] = v;
    }
    __syncthreads();
    long base = (long)s * 512 * 512;
#pragma unroll
    for (int r = 0; r < 4; ++r) {
        int n = n0 + ty + r * 8;
        float v = tile[tx][ty + r * 8];
        unsigned short h = f32_to_bf16_rn(v);
        Bhi[base + (long)n * 512 + k0 + tx] = (short)h;
        Blo[base + (long)n * 512 + k0 + tx] = (short)f32_to_bf16_rn(v - bf16_to_f32(h));
    }
}

// ---------------- prep: W2 [512][10] f32 -> transposed fp16 [16][512] (o-pad) ------
__global__ void prep_w2t(const float* __restrict__ W2, _Float16* __restrict__ W2h) {
    int idx = blockIdx.x * 256 + threadIdx.x;             // over 16*512
    int o = idx >> 9, k = idx & 511;
    float v = (o < 10) ? W2[k * 10 + o] : 0.0f;
    W2h[idx] = (_Float16)v;
}

// ---------------- split-precision bf16 MFMA GEMM, sigmoid epilogue ----------------
// A: [M][K] hi/lo bf16 (k-contig), B: [N][K] hi/lo bf16 (B^T layout, k-contig)
// C = sigmoid(A @ B^T). OMODE 1: hi/lo bf16 split out; OMODE 2: fp16 out.
template <int BM, int BN, int KSTEPS, int OMODE>
__global__ __launch_bounds__(256, 2)
void gemm_split(const short* __restrict__ Ahi, const short* __restrict__ Alo, int lda,
                const short* __restrict__ Bhi, const short* __restrict__ Blo, int ldb,
                void* __restrict__ out1, void* __restrict__ out2, int ldc,
                long strideB, long strideC) {
    constexpr int MI = BM / 32;           // frags per wave in M (wave covers BM/2)
    constexpr int NI = BN / 32;
    constexpr int AISS = (BM * 32) / (256 * 8);   // 4KB global_load_lds rounds per tile
    constexpr int BISS = (BN * 32) / (256 * 8);

    __shared__ __align__(16) short As[2][BM * 32];   // [hi/lo][row][k] linear
    __shared__ __align__(16) short Bs[2][BN * 32];

    const int tid  = threadIdx.x;
    const int wave = tid >> 6;
    const int lane = tid & 63;
    const int wm = wave >> 1, wn = wave & 1;          // 2x2 wave grid
    const int fr = lane & 15, fg = lane >> 4;         // frag row/col, k-group

    const int row0 = blockIdx.y * BM;
    const int col0 = blockIdx.x * BN;
    const long zb = (long)blockIdx.z * strideB;
    const long zc = (long)blockIdx.z * strideC;
    const short* pA[2] = {Ahi, Alo};
    const short* pB[2] = {Bhi + zb, Blo + zb};

    f32x4 acc[MI][NI] = {};

    for (int kb = 0; kb < KSTEPS; ++kb) {
        __syncthreads();                               // prev compute done before overwrite
#pragma unroll
        for (int h = 0; h < 2; ++h) {
#pragma unroll
            for (int i = 0; i < AISS; ++i) {
                int slot = i * 256 + tid;
                int r = slot >> 2, ch = slot & 3;      // 4 lanes per 64B row
                const short* src = pA[h] + (long)(row0 + r) * lda + kb * 32 + ch * 8;
                short* dst = &As[h][(i * 256 + wave * 64) * 8];   // wave-uniform base
                gload_lds16(src, dst);
            }
#pragma unroll
            for (int i = 0; i < BISS; ++i) {
                int slot = i * 256 + tid;
                int r = slot >> 2, ch = slot & 3;
                const short* src = pB[h] + (long)(col0 + r) * ldb + kb * 32 + ch * 8;
                short* dst = &Bs[h][(i * 256 + wave * 64) * 8];
                gload_lds16(src, dst);
            }
        }
        __syncthreads();                               // compiler drains vmcnt here

        short8 ah[MI], al[MI], bh[NI], bl[NI];
#pragma unroll
        for (int mi = 0; mi < MI; ++mi) {
            int r = wm * (BM / 2) + mi * 16 + fr;
            ah[mi] = *(const short8*)&As[0][r * 32 + fg * 8];
            al[mi] = *(const short8*)&As[1][r * 32 + fg * 8];
        }
#pragma unroll
        for (int ni = 0; ni < NI; ++ni) {
            int c = wn * (BN / 2) + ni * 16 + fr;
            bh[ni] = *(const short8*)&Bs[0][c * 32 + fg * 8];
            bl[ni] = *(const short8*)&Bs[1][c * 32 + fg * 8];
        }
#pragma unroll
        for (int mi = 0; mi < MI; ++mi)
#pragma unroll
            for (int ni = 0; ni < NI; ++ni) {
                acc[mi][ni] = __builtin_amdgcn_mfma_f32_16x16x32_bf16(ah[mi], bh[ni], acc[mi][ni], 0, 0, 0);
                acc[mi][ni] = __builtin_amdgcn_mfma_f32_16x16x32_bf16(ah[mi], bl[ni], acc[mi][ni], 0, 0, 0);
                acc[mi][ni] = __builtin_amdgcn_mfma_f32_16x16x32_bf16(al[mi], bh[ni], acc[mi][ni], 0, 0, 0);
            }
    }

    // epilogue: D row = fg*4+j, col = fr  (m89-verified layout), fused sigmoid
#pragma unroll
    for (int mi = 0; mi < MI; ++mi)
#pragma unroll
        for (int ni = 0; ni < NI; ++ni)
#pragma unroll
            for (int j = 0; j < 4; ++j) {
                int r = row0 + wm * (BM / 2) + mi * 16 + fg * 4 + j;
                int c = col0 + wn * (BN / 2) + ni * 16 + fr;
                float v = sigmoidf_(acc[mi][ni][j]);
                if constexpr (OMODE == 1) {
                    unsigned short h = f32_to_bf16_rn(v);
                    ((unsigned short*)out1)[(long)r * ldc + c] = h;
                    ((unsigned short*)out2)[(long)r * ldc + c] = f32_to_bf16_rn(v - bf16_to_f32(h));
                } else {
                    ((_Float16*)out1)[zc + (long)r * ldc + c] = (_Float16)v;
                }
            }
}

// ------ layer 2: out = sigmoid(C1h @ W2), fp16 MFMA, M=32768 N=16(10) K=512 -------
__global__ __launch_bounds__(256, 2)
void layer2_mfma(const _Float16* __restrict__ C1h, const _Float16* __restrict__ W2h,
                 float* __restrict__ out) {
    __shared__ __align__(16) _Float16 W2s[16 * 520];   // [o][k], stride 520 (2-way banked)
    const int tid = threadIdx.x;
    for (int i = tid; i < 16 * 512; i += 256) {
        int o = i >> 9, k = i & 511;
        W2s[o * 520 + k] = W2h[i];
    }
    __syncthreads();
    const int wave = tid >> 6, lane = tid & 63;
    const int fr = lane & 15, fg = lane >> 4;
    const long r0 = (long)blockIdx.x * 128 + wave * 32;   // 32 rows per wave
    f32x4 acc[2] = {};
    for (int kk = 0; kk < 16; ++kk) {
        half8 b = *(const half8*)&W2s[fr * 520 + kk * 32 + fg * 8];
#pragma unroll
        for (int fi = 0; fi < 2; ++fi) {
            half8 a = *(const half8*)&C1h[(r0 + fi * 16 + fr) * 512 + kk * 32 + fg * 8];
            acc[fi] = __builtin_amdgcn_mfma_f32_16x16x32_f16(a, b, acc[fi], 0, 0, 0);
        }
    }
    if (fr < 10) {
#pragma unroll
        for (int fi = 0; fi < 2; ++fi)
#pragma unroll
            for (int j = 0; j < 4; ++j) {
                long r = r0 + fi * 16 + fg * 4 + j;
                out[r * 10 + fr] = sigmoidf_(acc[fi][j]);
            }
    }
}

extern "C" void kernel_launch(void* const* d_in, const int* in_sizes, int n_in,
                              void* d_out, int out_size, void* d_ws, size_t ws_size,
                              hipStream_t stream) {
    const float* batch  = (const float*)d_in[0];
    const float* W0     = (const float*)d_in[1];
    const float* W1     = (const float*)d_in[2];
    const float* W2     = (const float*)d_in[3];
    const float* noise1 = (const float*)d_in[4];

    // ws layout (bytes), total 62,734,336
    if (ws_size < 62734336UL) return;   // undersized-ws signature: output stays poisoned
    char* ws = (char*)d_ws;
    short*    A0hi = (short*)(ws + 0);          // 2048*800*2 = 3,276,800
    short*    A0lo = (short*)(ws + 3276800);
    short*    B0hi = (short*)(ws + 6553600);    // 512*800*2 = 819,200
    short*    B0lo = (short*)(ws + 7372800);
    short*    B1hi = (short*)(ws + 8192000);    // 16*512*512*2 = 8,388,608
    short*    B1lo = (short*)(ws + 16580608);
    short*    C0hi = (short*)(ws + 24969216);   // 2048*512*2 = 2,097,152
    short*    C0lo = (short*)(ws + 27066368);
    _Float16* W2h  = (_Float16*)(ws + 29163520);// 16*512*2 = 16,384
    _Float16* C1h  = (_Float16*)(ws + 29179904);// 16*2048*512*2 = 33,554,432
    float*    out  = (float*)d_out;

    prep_batch<<<6400, 256, 0, stream>>>(batch, A0hi, A0lo);
    prep_w0t<<<dim3(16, 25), dim3(32, 8), 0, stream>>>(W0, B0hi, B0lo);
    prep_w1t<<<dim3(16, 16, 16), dim3(32, 8), 0, stream>>>(W1, noise1, B1hi, B1lo);
    prep_w2t<<<32, 256, 0, stream>>>(W2, W2h);

    // layer 0: sigmoid(batch @ W0) once (shared across replicas), split bf16 out
    gemm_split<64, 64, 25, 1><<<dim3(8, 32, 1), 256, 0, stream>>>(
        A0hi, A0lo, 800, B0hi, B0lo, 800,
        C0hi, C0lo, 512, 0, 0);

    // layer 1: per-replica sigmoid(C0 @ W1n[s]), fp16 out
    gemm_split<128, 128, 16, 2><<<dim3(4, 16, 16), 256, 0, stream>>>(
        C0hi, C0lo, 512, B1hi, B1lo, 512,
        C1h, nullptr, 512, 262144L, 1048576L);

    // layer 2: sigmoid(C1 @ W2) via fp16 MFMA
    layer2_mfma<<<256, 256, 0, stream>>>(C1h, W2h, out);
}

// Round 4
// 169.526 us; speedup vs baseline: 1.0287x; 1.0287x over previous
//
#include <hip/hip_runtime.h>
#include <hip/hip_bf16.h>
#include <stdint.h>

typedef __attribute__((ext_vector_type(8))) short short8;
typedef __attribute__((ext_vector_type(8))) _Float16 half8;
typedef __attribute__((ext_vector_type(4))) float f32x4;

__device__ __forceinline__ unsigned short f32_to_bf16_rn(float f) {
    unsigned int u = __float_as_uint(f);
    u += 0x7fffu + ((u >> 16) & 1u);
    return (unsigned short)(u >> 16);
}
__device__ __forceinline__ float bf16_to_f32(unsigned short h) {
    return __uint_as_float(((unsigned int)h) << 16);
}
__device__ __forceinline__ float sigmoidf_(float x) {
    return 1.0f / (1.0f + expf(-x));
}
__device__ __forceinline__ void gload_lds16(const short* g, short* l) {
    __builtin_amdgcn_global_load_lds(
        (const __attribute__((address_space(1))) void*)g,
        (__attribute__((address_space(3))) void*)l, 16, 0, 0);
}

// ---------------- prep: batch [2048][784] f32 -> hi/lo bf16 [2048][832] (k-pad) ----
__global__ void prep_batch(const float* __restrict__ batch,
                           short* __restrict__ Ahi, short* __restrict__ Alo) {
    long idx = (long)blockIdx.x * 256 + threadIdx.x;      // over 2048*832
    if (idx >= 2048L * 832) return;
    long m = idx / 832;
    int  k = (int)(idx - m * 832);
    float v = (k < 784) ? batch[m * 784 + k] : 0.0f;
    unsigned short h = f32_to_bf16_rn(v);
    Ahi[idx] = (short)h;
    Alo[idx] = (short)f32_to_bf16_rn(v - bf16_to_f32(h));
}

// ---------------- prep: W0 [784][512] -> transposed hi/lo [512][832] (k-pad) -------
__global__ void prep_w0t(const float* __restrict__ W0,
                         short* __restrict__ Bhi, short* __restrict__ Blo) {
    __shared__ float tile[32][33];
    int n0 = blockIdx.x * 32, k0 = blockIdx.y * 32;
    int tx = threadIdx.x, ty = threadIdx.y;               // (32,8)
#pragma unroll
    for (int r = 0; r < 4; ++r) {
        int k = k0 + ty + r * 8;
        float v = (k < 784) ? W0[(long)k * 512 + n0 + tx] : 0.0f;
        tile[ty + r * 8][tx] = v;
    }
    __syncthreads();
#pragma unroll
    for (int r = 0; r < 4; ++r) {
        int n = n0 + ty + r * 8;
        float v = tile[tx][ty + r * 8];
        unsigned short h = f32_to_bf16_rn(v);
        Bhi[(long)n * 832 + k0 + tx] = (short)h;
        Blo[(long)n * 832 + k0 + tx] = (short)f32_to_bf16_rn(v - bf16_to_f32(h));
    }
}

// ------- prep: W1n[s] = W1 + noise[s] (s=0 clean) -> transposed hi/lo [s][512][512] -
__global__ void prep_w1t(const float* __restrict__ W1, const float* __restrict__ noise,
                         short* __restrict__ Bhi, short* __restrict__ Blo) {
    __shared__ float tile[32][33];
    int n0 = blockIdx.x * 32, k0 = blockIdx.y * 32, s = blockIdx.z;
    int tx = threadIdx.x, ty = threadIdx.y;               // (32,8)
#pragma unroll
    for (int r = 0; r < 4; ++r) {
        int k = k0 + ty + r * 8;
        float v = W1[(long)k * 512 + n0 + tx];
        if (s > 0) v += noise[((long)s * 512 + k) * 512 + n0 + tx];
        tile[ty + r * 8][tx] = v;
    }
    __syncthreads();
    long base = (long)s * 512 * 512;
#pragma unroll
    for (int r = 0; r < 4; ++r) {
        int n = n0 + ty + r * 8;
        float v = tile[tx][ty + r * 8];
        unsigned short h = f32_to_bf16_rn(v);
        Bhi[base + (long)n * 512 + k0 + tx] = (short)h;
        Blo[base + (long)n * 512 + k0 + tx] = (short)f32_to_bf16_rn(v - bf16_to_f32(h));
    }
}

// ---------------- prep: W2 [512][10] f32 -> transposed fp16 [16][512] (o-pad) ------
__global__ void prep_w2t(const float* __restrict__ W2, _Float16* __restrict__ W2h) {
    int idx = blockIdx.x * 256 + threadIdx.x;             // over 16*512
    int o = idx >> 9, k = idx & 511;
    float v = (o < 10) ? W2[k * 10 + o] : 0.0f;
    W2h[idx] = (_Float16)v;
}

// ---------------- split-precision bf16 MFMA GEMM ----------------------------------
// A: [M][K] hi/lo bf16 (k-contig), B: [N][K] hi/lo bf16 (B^T layout, k-contig)
// OMODE 0: raw f32 partial to out1 (+ zc), no sigmoid (split-K partial)
// OMODE 2: fp16 sigmoid(out) to out1 (+ zc)
template <int BM, int BN, int KSTEPS, int OMODE>
__global__ __launch_bounds__(256, 2)
void gemm_split(const short* __restrict__ Ahi, const short* __restrict__ Alo, int lda,
                const short* __restrict__ Bhi, const short* __restrict__ Blo, int ldb,
                void* __restrict__ out1, int ldc,
                long strideB, long strideC, int kOffPerZ) {
    constexpr int MI = BM / 32;           // frags per wave in M (wave covers BM/2)
    constexpr int NI = BN / 32;
    constexpr int AISS = (BM * 32) / (256 * 8);   // 4KB global_load_lds rounds per tile
    constexpr int BISS = (BN * 32) / (256 * 8);

    __shared__ __align__(16) short As[2][BM * 32];   // [hi/lo][row][k] linear
    __shared__ __align__(16) short Bs[2][BN * 32];

    const int tid  = threadIdx.x;
    const int wave = tid >> 6;
    const int lane = tid & 63;
    const int wm = wave >> 1, wn = wave & 1;          // 2x2 wave grid
    const int fr = lane & 15, fg = lane >> 4;         // frag row/col, k-group

    const int row0 = blockIdx.y * BM;
    const int col0 = blockIdx.x * BN;
    const int kOff = kOffPerZ * blockIdx.z;
    const long zb = (long)blockIdx.z * strideB;
    const long zc = (long)blockIdx.z * strideC;
    const short* pA[2] = {Ahi, Alo};
    const short* pB[2] = {Bhi + zb, Blo + zb};

    f32x4 acc[MI][NI] = {};

    for (int kb = 0; kb < KSTEPS; ++kb) {
        __syncthreads();                               // prev compute done before overwrite
#pragma unroll
        for (int h = 0; h < 2; ++h) {
#pragma unroll
            for (int i = 0; i < AISS; ++i) {
                int slot = i * 256 + tid;
                int r = slot >> 2, ch = slot & 3;      // 4 lanes per 64B row
                const short* src = pA[h] + (long)(row0 + r) * lda + kOff + kb * 32 + ch * 8;
                short* dst = &As[h][(i * 256 + wave * 64) * 8];   // wave-uniform base
                gload_lds16(src, dst);
            }
#pragma unroll
            for (int i = 0; i < BISS; ++i) {
                int slot = i * 256 + tid;
                int r = slot >> 2, ch = slot & 3;
                const short* src = pB[h] + (long)(col0 + r) * ldb + kOff + kb * 32 + ch * 8;
                short* dst = &Bs[h][(i * 256 + wave * 64) * 8];
                gload_lds16(src, dst);
            }
        }
        __syncthreads();                               // compiler drains vmcnt here

        short8 ah[MI], al[MI], bh[NI], bl[NI];
#pragma unroll
        for (int mi = 0; mi < MI; ++mi) {
            int r = wm * (BM / 2) + mi * 16 + fr;
            ah[mi] = *(const short8*)&As[0][r * 32 + fg * 8];
            al[mi] = *(const short8*)&As[1][r * 32 + fg * 8];
        }
#pragma unroll
        for (int ni = 0; ni < NI; ++ni) {
            int c = wn * (BN / 2) + ni * 16 + fr;
            bh[ni] = *(const short8*)&Bs[0][c * 32 + fg * 8];
            bl[ni] = *(const short8*)&Bs[1][c * 32 + fg * 8];
        }
#pragma unroll
        for (int mi = 0; mi < MI; ++mi)
#pragma unroll
            for (int ni = 0; ni < NI; ++ni) {
                acc[mi][ni] = __builtin_amdgcn_mfma_f32_16x16x32_bf16(ah[mi], bh[ni], acc[mi][ni], 0, 0, 0);
                acc[mi][ni] = __builtin_amdgcn_mfma_f32_16x16x32_bf16(ah[mi], bl[ni], acc[mi][ni], 0, 0, 0);
                acc[mi][ni] = __builtin_amdgcn_mfma_f32_16x16x32_bf16(al[mi], bh[ni], acc[mi][ni], 0, 0, 0);
            }
    }

    // epilogue: D row = fg*4+j, col = fr  (m89-verified layout)
#pragma unroll
    for (int mi = 0; mi < MI; ++mi)
#pragma unroll
        for (int ni = 0; ni < NI; ++ni)
#pragma unroll
            for (int j = 0; j < 4; ++j) {
                int r = row0 + wm * (BM / 2) + mi * 16 + fg * 4 + j;
                int c = col0 + wn * (BN / 2) + ni * 16 + fr;
                if constexpr (OMODE == 0) {
                    ((float*)out1)[zc + (long)r * ldc + c] = acc[mi][ni][j];
                } else {
                    ((_Float16*)out1)[zc + (long)r * ldc + c] = (_Float16)sigmoidf_(acc[mi][ni][j]);
                }
            }
}

// -------- layer0 finalize: C0 = split_bf16(sigmoid(P0 + P1)), 2048x512 ------------
__global__ void c0_final(const float* __restrict__ P,
                         short* __restrict__ Chi, short* __restrict__ Clo) {
    int idx = blockIdx.x * 256 + threadIdx.x;             // over 1,048,576
    float v = P[idx] + P[idx + (1 << 20)];
    float s = sigmoidf_(v);
    unsigned short h = f32_to_bf16_rn(s);
    Chi[idx] = (short)h;
    Clo[idx] = (short)f32_to_bf16_rn(s - bf16_to_f32(h));
}

// ------ layer 2: out = sigmoid(C1h @ W2), fp16 MFMA, M=32768 N=16(10) K=512 -------
__global__ __launch_bounds__(256, 2)
void layer2_mfma(const _Float16* __restrict__ C1h, const _Float16* __restrict__ W2h,
                 float* __restrict__ out) {
    __shared__ __align__(16) _Float16 W2s[16 * 520];   // [o][k], stride 520 (2-way banked)
    const int tid = threadIdx.x;
    for (int i = tid; i < 16 * 512; i += 256) {
        int o = i >> 9, k = i & 511;
        W2s[o * 520 + k] = W2h[i];
    }
    __syncthreads();
    const int wave = tid >> 6, lane = tid & 63;
    const int fr = lane & 15, fg = lane >> 4;
    const long r0 = (long)blockIdx.x * 64 + wave * 16;    // 16 rows per wave
    f32x4 acc = {};
    for (int kk = 0; kk < 16; ++kk) {
        half8 b = *(const half8*)&W2s[fr * 520 + kk * 32 + fg * 8];
        half8 a = *(const half8*)&C1h[(r0 + fr) * 512 + kk * 32 + fg * 8];
        acc = __builtin_amdgcn_mfma_f32_16x16x32_f16(a, b, acc, 0, 0, 0);
    }
    if (fr < 10) {
#pragma unroll
        for (int j = 0; j < 4; ++j) {
            long r = r0 + fg * 4 + j;
            out[r * 10 + fr] = sigmoidf_(acc[j]);
        }
    }
}

extern "C" void kernel_launch(void* const* d_in, const int* in_sizes, int n_in,
                              void* d_out, int out_size, void* d_ws, size_t ws_size,
                              hipStream_t stream) {
    const float* batch  = (const float*)d_in[0];
    const float* W0     = (const float*)d_in[1];
    const float* W1     = (const float*)d_in[2];
    const float* W2     = (const float*)d_in[3];
    const float* noise1 = (const float*)d_in[4];

    // ws layout (bytes), total 63,062,016
    if (ws_size < 63062016UL) return;   // undersized-ws signature: output stays poisoned
    char* ws = (char*)d_ws;
    short*    A0hi = (short*)(ws + 0);          // 2048*832*2 = 3,407,872
    short*    A0lo = (short*)(ws + 3407872);
    short*    B0hi = (short*)(ws + 6815744);    // 512*832*2 = 851,968
    short*    B0lo = (short*)(ws + 7667712);
    short*    B1hi = (short*)(ws + 8519680);    // 16*512*512*2 = 8,388,608
    short*    B1lo = (short*)(ws + 16908288);
    short*    C0hi = (short*)(ws + 25296896);   // 2048*512*2 = 2,097,152
    short*    C0lo = (short*)(ws + 27394048);
    _Float16* W2h  = (_Float16*)(ws + 29491200);// 16*512*2 = 16,384
    _Float16* C1h  = (_Float16*)(ws + 29507584);// 16*2048*512*2 = 33,554,432
    float*    P0   = (float*)C1h;               // layer0 split-K partials alias C1h
    float*    out  = (float*)d_out;             // (used strictly before layer1 runs)

    prep_batch<<<6656, 256, 0, stream>>>(batch, A0hi, A0lo);
    prep_w0t<<<dim3(16, 26), dim3(32, 8), 0, stream>>>(W0, B0hi, B0lo);
    prep_w1t<<<dim3(16, 16, 16), dim3(32, 8), 0, stream>>>(W1, noise1, B1hi, B1lo);
    prep_w2t<<<32, 256, 0, stream>>>(W2, W2h);

    // layer 0: z = batch @ W0, split-K x2 (K=832 padded, 2x13 steps), raw f32 partials
    gemm_split<64, 64, 13, 0><<<dim3(8, 32, 2), 256, 0, stream>>>(
        A0hi, A0lo, 832, B0hi, B0lo, 832,
        P0, 512, 0, 1048576L, 416);
    // finalize: sigmoid(P0+P1) -> split bf16 C0
    c0_final<<<4096, 256, 0, stream>>>(P0, C0hi, C0lo);

    // layer 1: per-replica sigmoid(C0 @ W1n[s]), fp16 out
    gemm_split<128, 128, 16, 2><<<dim3(4, 16, 16), 256, 0, stream>>>(
        C0hi, C0lo, 512, B1hi, B1lo, 512,
        C1h, 512, 262144L, 1048576L, 0);

    // layer 2: sigmoid(C1 @ W2) via fp16 MFMA
    layer2_mfma<<<512, 256, 0, stream>>>(C1h, W2h, out);
}

// Round 10
// 137.771 us; speedup vs baseline: 1.2658x; 1.2305x over previous
//
#include <hip/hip_runtime.h>
#include <hip/hip_bf16.h>
#include <stdint.h>

typedef __attribute__((ext_vector_type(8))) _Float16 half8;
typedef __attribute__((ext_vector_type(4))) float f32x4;

__device__ __forceinline__ float sigmoidf_(float x) {
    return 1.0f / (1.0f + expf(-x));
}
__device__ __forceinline__ void gload_lds16(const _Float16* g, _Float16* l) {
    __builtin_amdgcn_global_load_lds(
        (const __attribute__((address_space(1))) void*)g,
        (__attribute__((address_space(3))) void*)l, 16, 0, 0);
}

// ---------------- prep: batch [2048][784] f32 -> fp16 [2048][832] (k-pad) ---------
__global__ void prep_batch(const float* __restrict__ batch, _Float16* __restrict__ A) {
    long idx = (long)blockIdx.x * 256 + threadIdx.x;      // over 2048*832
    if (idx >= 2048L * 832) return;
    long m = idx / 832;
    int  k = (int)(idx - m * 832);
    A[idx] = (_Float16)((k < 784) ? batch[m * 784 + k] : 0.0f);
}

// ---------------- prep: W0 [784][512] -> transposed fp16 [512][832] (k-pad) -------
__global__ void prep_w0t(const float* __restrict__ W0, _Float16* __restrict__ B) {
    __shared__ float tile[32][33];
    int n0 = blockIdx.x * 32, k0 = blockIdx.y * 32;
    int tx = threadIdx.x, ty = threadIdx.y;               // (32,8)
#pragma unroll
    for (int r = 0; r < 4; ++r) {
        int k = k0 + ty + r * 8;
        tile[ty + r * 8][tx] = (k < 784) ? W0[(long)k * 512 + n0 + tx] : 0.0f;
    }
    __syncthreads();
#pragma unroll
    for (int r = 0; r < 4; ++r) {
        int n = n0 + ty + r * 8;
        B[(long)n * 832 + k0 + tx] = (_Float16)tile[tx][ty + r * 8];
    }
}

// ------- prep: W1n[s] = W1 + noise[s] (s=0 clean) -> transposed fp16 [s][512][512] -
__global__ void prep_w1t(const float* __restrict__ W1, const float* __restrict__ noise,
                         _Float16* __restrict__ B) {
    __shared__ float tile[32][33];
    int n0 = blockIdx.x * 32, k0 = blockIdx.y * 32, s = blockIdx.z;
    int tx = threadIdx.x, ty = threadIdx.y;               // (32,8)
#pragma unroll
    for (int r = 0; r < 4; ++r) {
        int k = k0 + ty + r * 8;
        float v = W1[(long)k * 512 + n0 + tx];
        if (s > 0) v += noise[((long)s * 512 + k) * 512 + n0 + tx];
        tile[ty + r * 8][tx] = v;
    }
    __syncthreads();
    long base = (long)s * 512 * 512;
#pragma unroll
    for (int r = 0; r < 4; ++r) {
        int n = n0 + ty + r * 8;
        B[base + (long)n * 512 + k0 + tx] = (_Float16)tile[tx][ty + r * 8];
    }
}

// ---------------- fp16 MFMA GEMM ---------------------------------------------------
// A: [M][K] fp16 (k-contig), B: [N][K] fp16 (B^T layout, k-contig)
// OMODE 0: raw f32 partial to out (+ zc), no sigmoid (split-K partial)
// OMODE 2: fp16 sigmoid(out) to out (+ zc)
template <int BM, int BN, int KSTEPS, int OMODE, int MINW>
__global__ __launch_bounds__(256, MINW)
void gemm_f16(const _Float16* __restrict__ A, int lda,
              const _Float16* __restrict__ B, int ldb,
              void* __restrict__ out, int ldc,
              long strideB, long strideC, int kOffPerZ) {
    constexpr int MI = BM / 32;           // frags per wave in M (wave covers BM/2)
    constexpr int NI = BN / 32;
    constexpr int AISS = (BM * 32) / (256 * 8);   // global_load_lds rounds per tile
    constexpr int BISS = (BN * 32) / (256 * 8);

    __shared__ __align__(16) _Float16 As[BM * 32];   // [row][k] linear
    __shared__ __align__(16) _Float16 Bs[BN * 32];

    const int tid  = threadIdx.x;
    const int wave = tid >> 6;
    const int lane = tid & 63;
    const int wm = wave >> 1, wn = wave & 1;          // 2x2 wave grid
    const int fr = lane & 15, fg = lane >> 4;         // frag row/col, k-group

    const int row0 = blockIdx.y * BM;
    const int col0 = blockIdx.x * BN;
    const int kOff = kOffPerZ * blockIdx.z;
    const _Float16* pB = B + (long)blockIdx.z * strideB;
    const long zc = (long)blockIdx.z * strideC;

    f32x4 acc[MI][NI] = {};

    for (int kb = 0; kb < KSTEPS; ++kb) {
        __syncthreads();                               // prev compute done before overwrite
#pragma unroll
        for (int i = 0; i < AISS; ++i) {
            int slot = i * 256 + tid;
            int r = slot >> 2, ch = slot & 3;          // 4 lanes per 64B row
            const _Float16* src = A + (long)(row0 + r) * lda + kOff + kb * 32 + ch * 8;
            _Float16* dst = &As[(i * 256 + wave * 64) * 8];   // wave-uniform base
            gload_lds16(src, dst);
        }
#pragma unroll
        for (int i = 0; i < BISS; ++i) {
            int slot = i * 256 + tid;
            int r = slot >> 2, ch = slot & 3;
            const _Float16* src = pB + (long)(col0 + r) * ldb + kOff + kb * 32 + ch * 8;
            _Float16* dst = &Bs[(i * 256 + wave * 64) * 8];
            gload_lds16(src, dst);
        }
        __syncthreads();                               // compiler drains vmcnt here

        half8 af[MI], bf[NI];
#pragma unroll
        for (int mi = 0; mi < MI; ++mi) {
            int r = wm * (BM / 2) + mi * 16 + fr;
            af[mi] = *(const half8*)&As[r * 32 + fg * 8];
        }
#pragma unroll
        for (int ni = 0; ni < NI; ++ni) {
            int c = wn * (BN / 2) + ni * 16 + fr;
            bf[ni] = *(const half8*)&Bs[c * 32 + fg * 8];
        }
#pragma unroll
        for (int mi = 0; mi < MI; ++mi)
#pragma unroll
            for (int ni = 0; ni < NI; ++ni)
                acc[mi][ni] = __builtin_amdgcn_mfma_f32_16x16x32_f16(af[mi], bf[ni], acc[mi][ni], 0, 0, 0);
    }

    // epilogue: D row = fg*4+j, col = fr  (m89-verified layout)
#pragma unroll
    for (int mi = 0; mi < MI; ++mi)
#pragma unroll
        for (int ni = 0; ni < NI; ++ni)
#pragma unroll
            for (int j = 0; j < 4; ++j) {
                int r = row0 + wm * (BM / 2) + mi * 16 + fg * 4 + j;
                int c = col0 + wn * (BN / 2) + ni * 16 + fr;
                if constexpr (OMODE == 0) {
                    ((float*)out)[zc + (long)r * ldc + c] = acc[mi][ni][j];
                } else {
                    ((_Float16*)out)[zc + (long)r * ldc + c] = (_Float16)sigmoidf_(acc[mi][ni][j]);
                }
            }
}

// -------- layer0 finalize: C0 = fp16(sigmoid(P0 + P1)), 2048x512 ------------------
__global__ void c0_final(const float* __restrict__ P, _Float16* __restrict__ C) {
    int idx = blockIdx.x * 256 + threadIdx.x;             // over 1,048,576
    float v = P[idx] + P[idx + (1 << 20)];
    C[idx] = (_Float16)sigmoidf_(v);
}

// ------ layer 2: out = sigmoid(C1h @ W2), fp16 MFMA, M=32768 N=16(10) K=512 -------
// W2 fp32 [512][10] loaded+transposed to LDS fp16 in-kernel (prep fused).
__global__ __launch_bounds__(256, 2)
void layer2_mfma(const _Float16* __restrict__ C1h, const float* __restrict__ W2,
                 float* __restrict__ out) {
    __shared__ __align__(16) _Float16 W2s[16 * 520];   // [o][k], stride 520 (2-way banked)
    const int tid = threadIdx.x;
    for (int i = tid; i < 16 * 520; i += 256) W2s[i] = (_Float16)0.0f;
    __syncthreads();
    for (int i = tid; i < 5120; i += 256) {            // W2 is [k][o]
        int k = i / 10, o = i - 10 * k;
        W2s[o * 520 + k] = (_Float16)W2[i];
    }
    __syncthreads();
    const int wave = tid >> 6, lane = tid & 63;
    const int fr = lane & 15, fg = lane >> 4;
    const long r0 = (long)blockIdx.x * 64 + wave * 16;    // 16 rows per wave
    f32x4 acc = {};
    for (int kk = 0; kk < 16; ++kk) {
        half8 b = *(const half8*)&W2s[fr * 520 + kk * 32 + fg * 8];
        half8 a = *(const half8*)&C1h[(r0 + fr) * 512 + kk * 32 + fg * 8];
        acc = __builtin_amdgcn_mfma_f32_16x16x32_f16(a, b, acc, 0, 0, 0);
    }
    if (fr < 10) {
#pragma unroll
        for (int j = 0; j < 4; ++j) {
            long r = r0 + fg * 4 + j;
            out[r * 10 + fr] = sigmoidf_(acc[j]);
        }
    }
}

extern "C" void kernel_launch(void* const* d_in, const int* in_sizes, int n_in,
                              void* d_out, int out_size, void* d_ws, size_t ws_size,
                              hipStream_t stream) {
    const float* batch  = (const float*)d_in[0];
    const float* W0     = (const float*)d_in[1];
    const float* W1     = (const float*)d_in[2];
    const float* W2     = (const float*)d_in[3];
    const float* noise1 = (const float*)d_in[4];

    // ws layout (bytes), total 48,300,032
    if (ws_size < 48300032UL) return;   // undersized-ws signature: output stays poisoned
    char* ws = (char*)d_ws;
    _Float16* A0h = (_Float16*)(ws + 0);          // 2048*832*2 = 3,407,872
    _Float16* B0h = (_Float16*)(ws + 3407872);    // 512*832*2  =   851,968
    _Float16* B1h = (_Float16*)(ws + 4259840);    // 16*512*512*2 = 8,388,608
    _Float16* C0h = (_Float16*)(ws + 12648448);   // 2048*512*2 = 2,097,152
    _Float16* C1h = (_Float16*)(ws + 14745600);   // 16*2048*512*2 = 33,554,432
    float*    P0  = (float*)C1h;                  // layer0 split-K partials (8.4 MB)
    float*    out = (float*)d_out;                // P0 consumed before layer1 writes C1h

    prep_batch<<<6656, 256, 0, stream>>>(batch, A0h);
    prep_w0t<<<dim3(16, 26), dim3(32, 8), 0, stream>>>(W0, B0h);
    prep_w1t<<<dim3(16, 16, 16), dim3(32, 8), 0, stream>>>(W1, noise1, B1h);

    // layer 0: z = batch @ W0, split-K x2 (K=832 padded, 2x13 steps), raw f32 partials
    gemm_f16<64, 64, 13, 0, 2><<<dim3(8, 32, 2), 256, 0, stream>>>(
        A0h, 832, B0h, 832, P0, 512, 0, 1048576L, 416);
    // finalize: sigmoid(P0+P1) -> fp16 C0
    c0_final<<<4096, 256, 0, stream>>>(P0, C0h);

    // layer 1: per-replica sigmoid(C0 @ W1n[s]), fp16 out
    gemm_f16<128, 128, 16, 2, 4><<<dim3(4, 16, 16), 256, 0, stream>>>(
        C0h, 512, B1h, 512, C1h, 512, 262144L, 1048576L, 0);

    // layer 2: sigmoid(C1 @ W2) via fp16 MFMA (W2 prep fused)
    layer2_mfma<<<512, 256, 0, stream>>>(C1h, W2, out);
}

// Round 14
// 130.844 us; speedup vs baseline: 1.3328x; 1.0529x over previous
//
#include <hip/hip_runtime.h>
#include <hip/hip_bf16.h>
#include <stdint.h>

typedef __attribute__((ext_vector_type(8))) _Float16 half8;
typedef __attribute__((ext_vector_type(4))) float f32x4;

__device__ __forceinline__ float sigmoidf_(float x) {
    return 1.0f / (1.0f + expf(-x));
}
__device__ __forceinline__ void gload_lds16(const _Float16* g, _Float16* l) {
    __builtin_amdgcn_global_load_lds(
        (const __attribute__((address_space(1))) void*)g,
        (__attribute__((address_space(3))) void*)l, 16, 0, 0);
}

// ---------------- merged prep kernel -----------------------------------------------
// blocks [0, 6656):        batch [2048][784] f32 -> fp16 A0h [2048][832] (k-pad)
// blocks [6656, 7072):     W0 [784][512] -> transposed fp16 B0h [512][832] (k-pad)
// blocks [7072, 11168):    W1n[s] = W1 + noise[s] (s=0 clean) -> fp16 B1h [s][512][512]
__global__ void prep_all(const float* __restrict__ batch, const float* __restrict__ W0,
                         const float* __restrict__ W1, const float* __restrict__ noise,
                         _Float16* __restrict__ A0h, _Float16* __restrict__ B0h,
                         _Float16* __restrict__ B1h) {
    __shared__ float tile[32][33];
    const int b = blockIdx.x;
    const int tid = threadIdx.x;
    if (b < 6656) {                               // batch pad+convert (elementwise)
        long idx = (long)b * 256 + tid;
        if (idx < 2048L * 832) {
            long m = idx / 832;
            int  k = (int)(idx - m * 832);
            A0h[idx] = (_Float16)((k < 784) ? batch[m * 784 + k] : 0.0f);
        }
        return;
    }
    const int tx = tid & 31, ty = tid >> 5;       // (32,8) view
    if (b < 7072) {                               // W0^T: 16 n-blocks x 26 k-blocks
        int bb = b - 6656;
        int n0 = (bb & 15) * 32, k0 = (bb >> 4) * 32;
#pragma unroll
        for (int r = 0; r < 4; ++r) {
            int k = k0 + ty + r * 8;
            tile[ty + r * 8][tx] = (k < 784) ? W0[(long)k * 512 + n0 + tx] : 0.0f;
        }
        __syncthreads();
#pragma unroll
        for (int r = 0; r < 4; ++r) {
            int n = n0 + ty + r * 8;
            B0h[(long)n * 832 + k0 + tx] = (_Float16)tile[tx][ty + r * 8];
        }
    } else {                                      // W1n^T: 16 n x 16 k x 16 s
        int bb = b - 7072;
        int n0 = (bb & 15) * 32, k0 = ((bb >> 4) & 15) * 32, s = bb >> 8;
#pragma unroll
        for (int r = 0; r < 4; ++r) {
            int k = k0 + ty + r * 8;
            float v = W1[(long)k * 512 + n0 + tx];
            if (s > 0) v += noise[((long)s * 512 + k) * 512 + n0 + tx];
            tile[ty + r * 8][tx] = v;
        }
        __syncthreads();
        long base = (long)s * 512 * 512;
#pragma unroll
        for (int r = 0; r < 4; ++r) {
            int n = n0 + ty + r * 8;
            B1h[base + (long)n * 512 + k0 + tx] = (_Float16)tile[tx][ty + r * 8];
        }
    }
}

// ---------------- fp16 MFMA GEMM ---------------------------------------------------
// A: [M][K] fp16 (k-contig), B: [N][K] fp16 (B^T layout, k-contig)
// OMODE 0: raw f32 partial to out (+ zc), no sigmoid (split-K partial)
// OMODE 2: fp16 sigmoid(out) to out (+ zc)
template <int BM, int BN, int KSTEPS, int OMODE, int MINW>
__global__ __launch_bounds__(256, MINW)
void gemm_f16(const _Float16* __restrict__ A, int lda,
              const _Float16* __restrict__ B, int ldb,
              void* __restrict__ out, int ldc,
              long strideB, long strideC, int kOffPerZ) {
    constexpr int MI = BM / 32;           // frags per wave in M (wave covers BM/2)
    constexpr int NI = BN / 32;
    constexpr int AISS = (BM * 32) / (256 * 8);   // global_load_lds rounds per tile
    constexpr int BISS = (BN * 32) / (256 * 8);

    __shared__ __align__(16) _Float16 As[BM * 32];   // [row][k] linear
    __shared__ __align__(16) _Float16 Bs[BN * 32];

    const int tid  = threadIdx.x;
    const int wave = tid >> 6;
    const int lane = tid & 63;
    const int wm = wave >> 1, wn = wave & 1;          // 2x2 wave grid
    const int fr = lane & 15, fg = lane >> 4;         // frag row/col, k-group

    const int row0 = blockIdx.y * BM;
    const int col0 = blockIdx.x * BN;
    const int kOff = kOffPerZ * blockIdx.z;
    const _Float16* pB = B + (long)blockIdx.z * strideB;
    const long zc = (long)blockIdx.z * strideC;

    f32x4 acc[MI][NI] = {};

    for (int kb = 0; kb < KSTEPS; ++kb) {
        __syncthreads();                               // prev compute done before overwrite
#pragma unroll
        for (int i = 0; i < AISS; ++i) {
            int slot = i * 256 + tid;
            int r = slot >> 2, ch = slot & 3;          // 4 lanes per 64B row
            const _Float16* src = A + (long)(row0 + r) * lda + kOff + kb * 32 + ch * 8;
            _Float16* dst = &As[(i * 256 + wave * 64) * 8];   // wave-uniform base
            gload_lds16(src, dst);
        }
#pragma unroll
        for (int i = 0; i < BISS; ++i) {
            int slot = i * 256 + tid;
            int r = slot >> 2, ch = slot & 3;
            const _Float16* src = pB + (long)(col0 + r) * ldb + kOff + kb * 32 + ch * 8;
            _Float16* dst = &Bs[(i * 256 + wave * 64) * 8];
            gload_lds16(src, dst);
        }
        __syncthreads();                               // compiler drains vmcnt here

        half8 af[MI], bf[NI];
#pragma unroll
        for (int mi = 0; mi < MI; ++mi) {
            int r = wm * (BM / 2) + mi * 16 + fr;
            af[mi] = *(const half8*)&As[r * 32 + fg * 8];
        }
#pragma unroll
        for (int ni = 0; ni < NI; ++ni) {
            int c = wn * (BN / 2) + ni * 16 + fr;
            bf[ni] = *(const half8*)&Bs[c * 32 + fg * 8];
        }
#pragma unroll
        for (int mi = 0; mi < MI; ++mi)
#pragma unroll
            for (int ni = 0; ni < NI; ++ni)
                acc[mi][ni] = __builtin_amdgcn_mfma_f32_16x16x32_f16(af[mi], bf[ni], acc[mi][ni], 0, 0, 0);
    }

    // epilogue: D row = fg*4+j, col = fr  (m89-verified layout)
#pragma unroll
    for (int mi = 0; mi < MI; ++mi)
#pragma unroll
        for (int ni = 0; ni < NI; ++ni)
#pragma unroll
            for (int j = 0; j < 4; ++j) {
                int r = row0 + wm * (BM / 2) + mi * 16 + fg * 4 + j;
                int c = col0 + wn * (BN / 2) + ni * 16 + fr;
                if constexpr (OMODE == 0) {
                    ((float*)out)[zc + (long)r * ldc + c] = acc[mi][ni][j];
                } else {
                    ((_Float16*)out)[zc + (long)r * ldc + c] = (_Float16)sigmoidf_(acc[mi][ni][j]);
                }
            }
}

// -------- layer0 finalize: C0 = fp16(sigmoid(P0 + P1)), 2048x512 ------------------
__global__ void c0_final(const float* __restrict__ P, _Float16* __restrict__ C) {
    int idx = blockIdx.x * 256 + threadIdx.x;             // over 1,048,576
    float v = P[idx] + P[idx + (1 << 20)];
    C[idx] = (_Float16)sigmoidf_(v);
}

// ------ layer 2: out = sigmoid(C1h @ W2), fp16 MFMA, M=32768 N=16(10) K=512 -------
// W2 fp32 [512][10] loaded+transposed to LDS fp16 in-kernel (prep fused).
__global__ __launch_bounds__(256, 2)
void layer2_mfma(const _Float16* __restrict__ C1h, const float* __restrict__ W2,
                 float* __restrict__ out) {
    __shared__ __align__(16) _Float16 W2s[16 * 520];   // [o][k], stride 520 (2-way banked)
    const int tid = threadIdx.x;
    for (int i = tid; i < 16 * 520; i += 256) W2s[i] = (_Float16)0.0f;
    __syncthreads();
    for (int i = tid; i < 5120; i += 256) {            // W2 is [k][o]
        int k = i / 10, o = i - 10 * k;
        W2s[o * 520 + k] = (_Float16)W2[i];
    }
    __syncthreads();
    const int wave = tid >> 6, lane = tid & 63;
    const int fr = lane & 15, fg = lane >> 4;
    const long r0 = (long)blockIdx.x * 64 + wave * 16;    // 16 rows per wave
    f32x4 acc = {};
    for (int kk = 0; kk < 16; ++kk) {
        half8 b = *(const half8*)&W2s[fr * 520 + kk * 32 + fg * 8];
        half8 a = *(const half8*)&C1h[(r0 + fr) * 512 + kk * 32 + fg * 8];
        acc = __builtin_amdgcn_mfma_f32_16x16x32_f16(a, b, acc, 0, 0, 0);
    }
    if (fr < 10) {
#pragma unroll
        for (int j = 0; j < 4; ++j) {
            long r = r0 + fg * 4 + j;
            out[r * 10 + fr] = sigmoidf_(acc[j]);
        }
    }
}

extern "C" void kernel_launch(void* const* d_in, const int* in_sizes, int n_in,
                              void* d_out, int out_size, void* d_ws, size_t ws_size,
                              hipStream_t stream) {
    const float* batch  = (const float*)d_in[0];
    const float* W0     = (const float*)d_in[1];
    const float* W1     = (const float*)d_in[2];
    const float* W2     = (const float*)d_in[3];
    const float* noise1 = (const float*)d_in[4];

    // ws layout (bytes), total 48,300,032
    if (ws_size < 48300032UL) return;   // undersized-ws signature: output stays poisoned
    char* ws = (char*)d_ws;
    _Float16* A0h = (_Float16*)(ws + 0);          // 2048*832*2 = 3,407,872
    _Float16* B0h = (_Float16*)(ws + 3407872);    // 512*832*2  =   851,968
    _Float16* B1h = (_Float16*)(ws + 4259840);    // 16*512*512*2 = 8,388,608
    _Float16* C0h = (_Float16*)(ws + 12648448);   // 2048*512*2 = 2,097,152
    _Float16* C1h = (_Float16*)(ws + 14745600);   // 16*2048*512*2 = 33,554,432
    float*    P0  = (float*)C1h;                  // layer0 split-K partials (8.4 MB)
    float*    out = (float*)d_out;                // P0 consumed before layer1 writes C1h

    // all input preps in ONE kernel (launch-count: 7 -> 5)
    prep_all<<<11168, 256, 0, stream>>>(batch, W0, W1, noise1, A0h, B0h, B1h);

    // layer 0: z = batch @ W0, split-K x2 (K=832 padded, 2x13 steps), raw f32 partials
    gemm_f16<64, 64, 13, 0, 2><<<dim3(8, 32, 2), 256, 0, stream>>>(
        A0h, 832, B0h, 832, P0, 512, 0, 1048576L, 416);
    // finalize: sigmoid(P0+P1) -> fp16 C0
    c0_final<<<4096, 256, 0, stream>>>(P0, C0h);

    // layer 1: per-replica sigmoid(C0 @ W1n[s]), fp16 out
    gemm_f16<128, 128, 16, 2, 4><<<dim3(4, 16, 16), 256, 0, stream>>>(
        C0h, 512, B1h, 512, C1h, 512, 262144L, 1048576L, 0);

    // layer 2: sigmoid(C1 @ W2) via fp16 MFMA (W2 prep fused)
    layer2_mfma<<<512, 256, 0, stream>>>(C1h, W2, out);
}